// Round 14
// baseline (96.780 us; speedup 1.0000x reference)
//
#include <hip/hip_runtime.h>
#include <math.h>

#define N_ 32
#define C_ 256
#define H_ 56
#define W_ 56
#define HW_ (H_*W_)          // 3136
#define HW4_ (HW_/4)         // 784
#define CHW_ (C_*HW_)        // 802816
#define NHW_ (N_*HW_)        // 100352
#define NHW4_ (NHW_/4)       // 25088
#define NCW_ (N_*C_*W_)      // 458752
#define NHC_ (N_*H_*C_)      // 458752
#define BN_EPS_ 1e-5f

#define PPB 8                // planes per block
#define NB_PL 1024           // 1024 blocks x 8 planes; 4 blocks/CU

#define F4MAX(a,b) do { (a).x=fmaxf((a).x,(b).x); (a).y=fmaxf((a).y,(b).y); \
                        (a).z=fmaxf((a).z,(b).z); (a).w=fmaxf((a).w,(b).w); } while(0)
#define F4ADD(a,b) do { (a).x+=(b).x; (a).y+=(b).y; (a).z+=(b).z; (a).w+=(b).w; } while(0)

typedef __attribute__((address_space(1))) const unsigned int GAS;
typedef __attribute__((address_space(3))) unsigned int LAS;

// ---- pools via global_load_lds: no register staging, no ds_write, 1 barrier/plane ----
__global__ __launch_bounds__(256, 4) void pools_k(
        const float* __restrict__ x,
        float* __restrict__ maxH, float* __restrict__ meanH,
        float* __restrict__ maxWt, float* __restrict__ meanWt,
        float* __restrict__ pmx, float* __restrict__ psm,
        float* __restrict__ y) {
    __shared__ float buf[2][HW_];          // two linear plane buffers (12544 B each)
    __shared__ float ys[8];                // [parity][wave] y partials
    const int b = blockIdx.x;
    const int tid = threadIdx.x;
    const int wave = tid >> 6;
    const int lane = tid & 63;
    const int n = b >> 5;                  // 32 blocks per n
    const int pb0 = b * PPB;
    const float4* x4 = (const float4*)x;

    float4 amx0, amx1, amx2, amx3, asm0, asm1, asm2, asm3;
    amx0 = amx1 = amx2 = amx3 = make_float4(-INFINITY, -INFINITY, -INFINITY, -INFINITY);
    asm0 = asm1 = asm2 = asm3 = make_float4(0.f, 0.f, 0.f, 0.f);

    // issue plane P into buf[par]: 12 full-wave 1KB chunks + 16-lane remainder
#define ISSUE(P, PAR) do {                                                         \
        size_t _gb = (size_t)(pb0 + (P)) * HW4_;                                   \
        _Pragma("unroll")                                                          \
        for (int _ch = 0; _ch < 3; ++_ch) {                                        \
            int _c = wave * 3 + _ch;                                               \
            __builtin_amdgcn_global_load_lds((GAS*)(x4 + _gb + _c * 64 + lane),    \
                                             (LAS*)&buf[PAR][_c * 256], 16, 0, 0); \
        }                                                                          \
        if (tid < 16)                                                              \
            __builtin_amdgcn_global_load_lds((GAS*)(x4 + _gb + 768 + lane),        \
                                             (LAS*)&buf[PAR][3072], 16, 0, 0);     \
    } while (0)

    ISSUE(0, 0);
    __syncthreads();

    #pragma unroll
    for (int k = 0; k < PPB; ++k) {
        const int par = k & 1;
        // issue next plane into the buffer freed by the previous barrier
        if (k + 1 < PPB) ISSUE(k + 1, par ^ 1);

        const float* tile = buf[par];
        const float4* tile4 = (const float4*)tile;
        const int pb = pb0 + k;
        const int c = pb & 255;

        // fold C-partials (per-thread fixed f4 slots)
        {
            float4 v0 = tile4[tid];
            float4 v1 = tile4[tid + 256];
            float4 v2 = tile4[tid + 512];
            F4MAX(amx0, v0); F4ADD(asm0, v0);
            F4MAX(amx1, v1); F4ADD(asm1, v1);
            F4MAX(amx2, v2); F4ADD(asm2, v2);
            if (tid < 16) {
                float4 v3 = tile4[tid + 768];
                F4MAX(amx3, v3); F4ADD(asm3, v3);
            }
        }
        // col phase: lane = 4w+hq; 14 rows each; combine in adjacent lanes
        float csm_full = 0.f;
        if (tid < 224) {
            int w = tid >> 2, hq = tid & 3;
            float cmx = -INFINITY, csm = 0.f;
            #pragma unroll
            for (int hh = 0; hh < 14; ++hh) {
                float v = tile[(hq * 14 + hh) * W_ + w];
                cmx = fmaxf(cmx, v); csm += v;
            }
            cmx = fmaxf(cmx, __shfl_xor(cmx, 1)); csm += __shfl_xor(csm, 1);
            cmx = fmaxf(cmx, __shfl_xor(cmx, 2)); csm += __shfl_xor(csm, 2);
            if (hq == 0) {
                int o = (n * C_ + c) * W_ + w;
                maxH[o] = cmx;
                meanH[o] = csm * (1.f / H_);
                csm_full = csm;
            }
        }
        // row phase: lane = 4h+kq; 14 cols each
        if (tid < 224) {
            int h = tid >> 2, kq = tid & 3;
            float rmx = -INFINITY, rsm = 0.f;
            #pragma unroll
            for (int j = 0; j < 14; ++j) {
                float v = tile[h * W_ + kq * 14 + j];
                rmx = fmaxf(rmx, v); rsm += v;
            }
            rmx = fmaxf(rmx, __shfl_xor(rmx, 1)); rsm += __shfl_xor(rsm, 1);
            rmx = fmaxf(rmx, __shfl_xor(rmx, 2)); rsm += __shfl_xor(rsm, 2);
            if (kq == 0) {
                int o = (n * C_ + c) * H_ + h;     // transposed, coalesced
                maxWt[o] = rmx;
                meanWt[o] = rsm * (1.f / W_);
            }
        }
        // y: wave partials of column sums, combined one plane later
        {
            float yp = csm_full;                   // nonzero only on hq==0 lanes
            #pragma unroll
            for (int off = 32; off >= 1; off >>= 1) yp += __shfl_xor(yp, off);
            if (lane == 0) ys[par * 4 + wave] = yp;
            if (k > 0 && tid == 0) {
                int s = (par ^ 1) * 4;
                float t = ys[s] + ys[s + 1] + ys[s + 2] + ys[s + 3];
                y[pb - 1] = t * (1.f / HW_);
            }
        }
        __syncthreads();
    }
    if (tid == 0) {
        int s = ((PPB - 1) & 1) * 4;
        float t = ys[s] + ys[s + 1] + ys[s + 2] + ys[s + 3];
        y[pb0 + PPB - 1] = t * (1.f / HW_);
    }
#undef ISSUE
    // write 8-channel C-partials, coalesced [b][hw4]
    {
        float4* PM = (float4*)pmx + (size_t)b * HW4_;
        float4* PS = (float4*)psm + (size_t)b * HW4_;
        PM[tid] = amx0;        PS[tid] = asm0;
        PM[tid + 256] = amx1;  PS[tid + 256] = asm1;
        PM[tid + 512] = amx2;  PS[tid + 512] = asm2;
        if (tid < 16) { PM[tid + 768] = amx3; PS[tid + 768] = asm3; }
    }
}

// ---- combine 32 c-group partials -> maxC/meanC; 392 blocks, full-chip ----
__global__ __launch_bounds__(256, 4) void cpool_final_k(
        const float* __restrict__ pmx, const float* __restrict__ psm,
        float* __restrict__ maxC, float* __restrict__ meanC) {
    __shared__ float4 smx[4][64];
    __shared__ float4 ssm[4][64];
    int bb = blockIdx.x;
    int tid = threadIdx.x;
    int oi = tid & 63, g4 = tid >> 6;
    int t = bb * 64 + oi;                          // 0..NHW4-1
    int n = t / HW4_, hw4 = t - n * HW4_;
    const float4* PM = (const float4*)pmx + (size_t)(n * 32 + g4 * 8) * HW4_ + hw4;
    const float4* PS = (const float4*)psm + (size_t)(n * 32 + g4 * 8) * HW4_ + hw4;
    float4 mx = make_float4(-INFINITY, -INFINITY, -INFINITY, -INFINITY);
    float4 sm = make_float4(0.f, 0.f, 0.f, 0.f);
    #pragma unroll
    for (int g = 0; g < 8; ++g) {
        float4 v = PM[(size_t)g * HW4_];
        float4 s = PS[(size_t)g * HW4_];
        F4MAX(mx, v);
        F4ADD(sm, s);
    }
    smx[g4][oi] = mx;
    ssm[g4][oi] = sm;
    __syncthreads();
    if (tid < 64) {
        float4 m = smx[0][tid];
        #pragma unroll
        for (int j = 1; j < 4; ++j) F4MAX(m, smx[j][tid]);
        ((float4*)maxC)[bb * 64 + tid] = m;
    } else if (tid < 128) {
        int t2 = tid - 64;
        float4 s = ssm[0][t2];
        #pragma unroll
        for (int j = 1; j < 4; ++j) F4ADD(s, ssm[j][t2]);
        s.x *= (1.f / C_); s.y *= (1.f / C_); s.z *= (1.f / C_); s.w *= (1.f / C_);
        ((float4*)meanC)[bb * 64 + t2] = s;
    }
}

// ---- conv 7x7 + BN + sigmoid; TR=true uses transposed kernel weights ----
template <int R, int Cc, bool TR>
__device__ __forceinline__ void conv7_part(int t, const float* __restrict__ p0,
                                           const float* __restrict__ p1,
                                           const float* __restrict__ wt,
                                           float g, float bb, float m, float v,
                                           float* __restrict__ out) {
    const int per = R * Cc;
    int n = t / per;
    int r2 = t - n * per;
    int i = r2 / Cc, j = r2 - i * Cc;
    const float* b0 = p0 + (size_t)n * per;
    const float* b1 = p1 + (size_t)n * per;
    float acc = 0.f;
    #pragma unroll
    for (int ki = 0; ki < 7; ++ki) {
        int ii = i + ki - 3;
        if (ii < 0 || ii >= R) continue;
        #pragma unroll
        for (int kj = 0; kj < 7; ++kj) {
            int jj = j + kj - 3;
            if (jj < 0 || jj >= Cc) continue;
            int idx = ii * Cc + jj;
            int wi = TR ? (kj * 7 + ki) : (ki * 7 + kj);
            acc += b0[idx] * wt[wi] + b1[idx] * wt[49 + wi];
        }
    }
    float o = (acc - m) * rsqrtf(v + BN_EPS_) * g + bb;
    out[t] = 1.f / (1.f + expf(-o));
}

#define NB_SS (NHW_ / 256)            // 392
#define NB_SH (NCW_ / 256)            // 1792
#define NB_SW (NHC_ / 256)            // 1792

// ---- fused: 3 gate convs + ECA sort/conv/unsort ----
__global__ __launch_bounds__(256) void conv_eca_k(
        const float* __restrict__ maxC, const float* __restrict__ meanC,
        const float* __restrict__ maxH, const float* __restrict__ meanH,
        const float* __restrict__ maxWt, const float* __restrict__ meanWt,
        const float* __restrict__ w_s, const float* __restrict__ g_s,
        const float* __restrict__ b_s, const float* __restrict__ m_s,
        const float* __restrict__ v_s,
        const float* __restrict__ w_h, const float* __restrict__ g_h,
        const float* __restrict__ b_h, const float* __restrict__ m_h,
        const float* __restrict__ v_h,
        const float* __restrict__ w_w, const float* __restrict__ g_w,
        const float* __restrict__ b_w, const float* __restrict__ m_w,
        const float* __restrict__ v_w,
        const float* __restrict__ y, const float* __restrict__ w_eca,
        float* __restrict__ s_s, float* __restrict__ s_h, float* __restrict__ s_wt,
        float* __restrict__ gate) {
    __shared__ float sv[C_];
    __shared__ int si[C_];
    int b = blockIdx.x;
    int tid = threadIdx.x;
    if (b < NB_SS) {
        conv7_part<H_, W_, false>(b * 256 + tid, maxC, meanC, w_s, g_s[0], b_s[0],
                                  m_s[0], v_s[0], s_s);
    } else if (b < NB_SS + NB_SH) {
        conv7_part<C_, W_, false>((b - NB_SS) * 256 + tid, maxH, meanH, w_h, g_h[0],
                                  b_h[0], m_h[0], v_h[0], s_h);
    } else if (b < NB_SS + NB_SH + NB_SW) {
        conv7_part<C_, H_, true>((b - NB_SS - NB_SH) * 256 + tid, maxWt, meanWt, w_w,
                                 g_w[0], b_w[0], m_w[0], v_w[0], s_wt);
    } else {
        int n = b - (NB_SS + NB_SH + NB_SW);
        sv[tid] = y[n * C_ + tid];
        si[tid] = tid;
        __syncthreads();
        for (int k = 2; k <= C_; k <<= 1) {
            for (int j = k >> 1; j > 0; j >>= 1) {
                int ixj = tid ^ j;
                if (ixj > tid) {
                    float v1 = sv[tid], v2 = sv[ixj];
                    int i1 = si[tid], i2 = si[ixj];
                    bool before = (v1 > v2) || (v1 == v2 && i1 < i2);
                    bool dir = ((tid & k) == 0);
                    if (dir ? !before : before) {
                        sv[tid] = v2; sv[ixj] = v1;
                        si[tid] = i2; si[ixj] = i1;
                    }
                }
                __syncthreads();
            }
        }
        float o = 0.f;
        #pragma unroll
        for (int j = 0; j < 5; ++j) {
            int p = tid + j - 2;
            if (p >= 0 && p < C_) o += sv[p] * w_eca[j];
        }
        gate[n * C_ + si[tid]] = 1.f / (1.f + expf(-o));
    }
}

// ---- final apply: 2 float4 per thread; s_wt read transposed ----
__global__ __launch_bounds__(256) void apply_k(
        const float* __restrict__ x, const float* __restrict__ s_s,
        const float* __restrict__ s_h, const float* __restrict__ s_wt,
        const float* __restrict__ gate, float* __restrict__ out) {
    int t0 = blockIdx.x * 512 + threadIdx.x;
    #pragma unroll
    for (int r = 0; r < 2; ++r) {
        int t = t0 + r * 256;
        int f = t * 4;
        int n = f / CHW_;
        int rem = f - n * CHW_;
        int c = rem / HW_;
        int hw = rem - c * HW_;
        int h = hw / W_;
        int w = hw - h * W_;
        float4 xv = ((const float4*)x)[t];
        float4 s4 = *(const float4*)(s_s + (size_t)n * HW_ + hw);
        float4 h4 = *(const float4*)(s_h + ((size_t)n * C_ + c) * W_ + w);
        float sw = s_wt[((size_t)n * C_ + c) * H_ + h];
        float ge = gate[n * C_ + c];
        float base = 0.24365f * sw + 0.27173f * ge;
        float4 o;
        o.x = xv.x * (0.23779f * s4.x + 0.24695f * h4.x + base);
        o.y = xv.y * (0.23779f * s4.y + 0.24695f * h4.y + base);
        o.z = xv.z * (0.23779f * s4.z + 0.24695f * h4.z + base);
        o.w = xv.w * (0.23779f * s4.w + 0.24695f * h4.w + base);
        ((float4*)out)[t] = o;
    }
}

extern "C" void kernel_launch(void* const* d_in, const int* in_sizes, int n_in,
                              void* d_out, int out_size, void* d_ws, size_t ws_size,
                              hipStream_t stream) {
    const float* x     = (const float*)d_in[0];
    const float* w_h   = (const float*)d_in[2];
    const float* g_h   = (const float*)d_in[3];
    const float* b_h   = (const float*)d_in[4];
    const float* m_h   = (const float*)d_in[5];
    const float* v_h   = (const float*)d_in[6];
    const float* w_w   = (const float*)d_in[7];
    const float* g_w   = (const float*)d_in[8];
    const float* b_w   = (const float*)d_in[9];
    const float* m_w   = (const float*)d_in[10];
    const float* v_w   = (const float*)d_in[11];
    const float* w_s   = (const float*)d_in[12];
    const float* g_s   = (const float*)d_in[13];
    const float* b_s   = (const float*)d_in[14];
    const float* m_s   = (const float*)d_in[15];
    const float* v_s   = (const float*)d_in[16];
    const float* w_eca = (const float*)d_in[17];
    float* out = (float*)d_out;

    float* ws    = (float*)d_ws;
    float* maxC  = ws;                  // NHW
    float* meanC = maxC  + NHW_;        // NHW
    float* maxH  = meanC + NHW_;        // NCW
    float* meanH = maxH  + NCW_;        // NCW
    float* maxWt = meanH + NCW_;        // NHC (stored [n][c][h])
    float* meanWt= maxWt + NHC_;        // NHC
    float* s_s   = meanWt+ NHC_;        // NHW
    float* s_h   = s_s   + NHW_;        // NCW
    float* s_wt  = s_h   + NCW_;        // NHC (stored [n][c][h])
    float* yv    = s_wt  + NHC_;        // N*C
    float* gate  = yv    + N_ * C_;     // N*C
    float* pmx   = gate  + N_ * C_;     // NB_PL * HW
    float* psm   = pmx   + (size_t)NB_PL * HW_;

    pools_k<<<NB_PL, 256, 0, stream>>>(x, maxH, meanH, maxWt, meanWt, pmx, psm, yv);

    cpool_final_k<<<NHW4_ / 64, 256, 0, stream>>>(pmx, psm, maxC, meanC);

    int conv_blocks = NB_SS + NB_SH + NB_SW + N_;
    conv_eca_k<<<conv_blocks, 256, 0, stream>>>(maxC, meanC, maxH, meanH, maxWt, meanWt,
                                                w_s, g_s, b_s, m_s, v_s,
                                                w_h, g_h, b_h, m_h, v_h,
                                                w_w, g_w, b_w, m_w, v_w,
                                                yv, w_eca, s_s, s_h, s_wt, gate);

    apply_k<<<(N_ * CHW_ / 4) / 512, 256, 0, stream>>>(x, s_s, s_h, s_wt, gate, out);
}